// Round 1
// baseline (3286.246 us; speedup 1.0000x reference)
//
#include <hip/hip_runtime.h>

#define N_NODES 50000

// ---------------------------------------------------------------------------
// Scatter: for each edge e, agg[dst] += feat[src] (128 floats), deg[dst] += 1.
// 32 threads per edge, one float4 each. unsafeAtomicAdd -> global_atomic_add_f32.
// ---------------------------------------------------------------------------
__global__ __launch_bounds__(256) void scatter_kernel(
    const float* __restrict__ feat,
    const int* __restrict__ ei,      // [2, E] int32: row 0 = src, row 1 = dst
    float* __restrict__ agg,         // [N, 128], pre-zeroed
    float* __restrict__ deg,         // [N] or nullptr, pre-zeroed
    int E)
{
    int gid = blockIdx.x * blockDim.x + threadIdx.x;
    int e = gid >> 5;
    if (e >= E) return;
    int c = gid & 31;

    int src = ei[e];
    int dst = ei[E + e];

    float4 v = reinterpret_cast<const float4*>(feat)[(size_t)src * 32 + c];
    float* a = agg + (size_t)dst * 128 + c * 4;
    unsafeAtomicAdd(a + 0, v.x);
    unsafeAtomicAdd(a + 1, v.y);
    unsafeAtomicAdd(a + 2, v.z);
    unsafeAtomicAdd(a + 3, v.w);
    if (deg != nullptr && c == 0) unsafeAtomicAdd(&deg[dst], 1.0f);
}

// ---------------------------------------------------------------------------
// Dense: out[n, :] = epilogue( (agg[n]/max(deg,1)) @ Wl^T + b + feat[n] @ Wr^T )
// K = 128 (both operand halves), M = 128 (relu) or 64 (log_softmax).
// Block: 256 threads = 16 nodes x 16 output-groups; PO = M/16 outputs/thread.
// ---------------------------------------------------------------------------
template <int M, int EPI>  // EPI: 0 = relu, 1 = log_softmax
__global__ __launch_bounds__(256) void dense_kernel(
    const float* __restrict__ agg,
    const float* __restrict__ feat,
    const float* __restrict__ deg,
    const float* __restrict__ Wl,   // [M,128]
    const float* __restrict__ b,    // [M]
    const float* __restrict__ Wr,   // [M,128]
    float* __restrict__ out)        // [N, M]
{
    constexpr int PO = M / 16;              // outputs per thread
    __shared__ float A[16][260];            // [node][k]; k<128 agg_mean, k>=128 feat; +4 pad

    const int t = threadIdx.x;
    const int nl = t >> 4;                  // node within block, 0..15
    const int oc = t & 15;                  // output group, 0..15
    const int gbase = blockIdx.x * 16;

    // Stage A tile: 16 nodes x 256 floats = 1024 float4, 4 per thread.
    for (int i = 0; i < 4; ++i) {
        int idx = i * 256 + t;              // 0..1023
        int row = idx >> 6;                 // 0..15
        int c4  = idx & 63;                 // float4 index within 256 floats
        int g = gbase + row;
        float4 v;
        if (c4 < 32) {
            v = reinterpret_cast<const float4*>(agg)[(size_t)g * 32 + c4];
            float id = 1.0f / fmaxf(deg[g], 1.0f);
            v.x *= id; v.y *= id; v.z *= id; v.w *= id;
        } else {
            v = reinterpret_cast<const float4*>(feat)[(size_t)g * 32 + (c4 - 32)];
        }
        reinterpret_cast<float4*>(&A[row][0])[c4] = v;
    }
    __syncthreads();

    float acc[PO];
#pragma unroll
    for (int j = 0; j < PO; ++j) acc[j] = b[oc * PO + j];

    // Phase 1: agg_mean @ Wl^T
#pragma unroll 4
    for (int k4 = 0; k4 < 32; ++k4) {
        float4 a = reinterpret_cast<const float4*>(&A[nl][0])[k4];
#pragma unroll
        for (int j = 0; j < PO; ++j) {
            float4 w = reinterpret_cast<const float4*>(Wl)[(oc * PO + j) * 32 + k4];
            acc[j] += a.x * w.x + a.y * w.y + a.z * w.z + a.w * w.w;
        }
    }
    // Phase 2: feat @ Wr^T
#pragma unroll 4
    for (int k4 = 0; k4 < 32; ++k4) {
        float4 a = reinterpret_cast<const float4*>(&A[nl][0])[32 + k4];
#pragma unroll
        for (int j = 0; j < PO; ++j) {
            float4 w = reinterpret_cast<const float4*>(Wr)[(oc * PO + j) * 32 + k4];
            acc[j] += a.x * w.x + a.y * w.y + a.z * w.z + a.w * w.w;
        }
    }

    const int g = gbase + nl;
    float* op = out + (size_t)g * M + oc * PO;

    if (EPI == 0) {
#pragma unroll
        for (int j = 0; j < PO; ++j) acc[j] = fmaxf(acc[j], 0.0f);
#pragma unroll
        for (int j4 = 0; j4 < PO / 4; ++j4) {
            float4 v = {acc[j4 * 4 + 0], acc[j4 * 4 + 1], acc[j4 * 4 + 2], acc[j4 * 4 + 3]};
            reinterpret_cast<float4*>(op)[j4] = v;
        }
    } else {
        // log_softmax over M outputs of this node, spread over 16 threads (same nl).
        float m = acc[0];
#pragma unroll
        for (int j = 1; j < PO; ++j) m = fmaxf(m, acc[j]);
#pragma unroll
        for (int s = 1; s < 16; s <<= 1) m = fmaxf(m, __shfl_xor(m, s, 16));
        float sum = 0.0f;
#pragma unroll
        for (int j = 0; j < PO; ++j) sum += expf(acc[j] - m);
#pragma unroll
        for (int s = 1; s < 16; s <<= 1) sum += __shfl_xor(sum, s, 16);
        float lse = m + logf(sum);
#pragma unroll
        for (int j4 = 0; j4 < PO / 4; ++j4) {
            float4 v = {acc[j4 * 4 + 0] - lse, acc[j4 * 4 + 1] - lse,
                        acc[j4 * 4 + 2] - lse, acc[j4 * 4 + 3] - lse};
            reinterpret_cast<float4*>(op)[j4] = v;
        }
    }
}

extern "C" void kernel_launch(void* const* d_in, const int* in_sizes, int n_in,
                              void* d_out, int out_size, void* d_ws, size_t ws_size,
                              hipStream_t stream)
{
    const float* x   = (const float*)d_in[0];
    const int*   ei  = (const int*)d_in[1];   // [2, E] int32
    const float* W1l = (const float*)d_in[2];
    const float* b1  = (const float*)d_in[3];
    const float* W1r = (const float*)d_in[4];
    const float* W2l = (const float*)d_in[5];
    const float* b2  = (const float*)d_in[6];
    const float* W2r = (const float*)d_in[7];
    float* out = (float*)d_out;

    const int E = in_sizes[1] / 2;

    // Workspace layout (floats): deg[N] | agg[N*128] | h[N*128]  (~51.4 MB)
    float* deg = (float*)d_ws;
    float* agg = deg + N_NODES;
    float* h   = agg + (size_t)N_NODES * 128;

    // Zero deg + agg (contiguous).
    hipMemsetAsync(deg, 0, (size_t)(N_NODES + (size_t)N_NODES * 128) * sizeof(float), stream);

    const int sc_threads = 256;
    const int sc_blocks = (int)(((size_t)E * 32 + sc_threads - 1) / sc_threads);

    // Layer 1
    scatter_kernel<<<sc_blocks, sc_threads, 0, stream>>>(x, ei, agg, deg, E);
    dense_kernel<128, 0><<<N_NODES / 16, 256, 0, stream>>>(agg, x, deg, W1l, b1, W1r, h);

    // Layer 2 (deg reused)
    hipMemsetAsync(agg, 0, (size_t)N_NODES * 128 * sizeof(float), stream);
    scatter_kernel<<<sc_blocks, sc_threads, 0, stream>>>(h, ei, agg, nullptr, E);
    dense_kernel<64, 1><<<N_NODES / 16, 256, 0, stream>>>(agg, h, deg, W2l, b2, W2r, out);
}

// Round 2
// 1372.239 us; speedup vs baseline: 2.3948x; 2.3948x over previous
//
#include <hip/hip_runtime.h>

#define N_NODES 50000

// ---------------------------------------------------------------------------
// CSR build: count -> scan -> fill. Edges sorted by dst so aggregation is a
// gather (register accumulation) instead of 164M float atomics.
// ---------------------------------------------------------------------------
__global__ __launch_bounds__(256) void count_kernel(
    const int* __restrict__ ei, int* __restrict__ cnt, int E)
{
    int e = blockIdx.x * blockDim.x + threadIdx.x;
    if (e < E) atomicAdd(&cnt[ei[E + e]], 1);
}

__global__ __launch_bounds__(1024) void scan_kernel(
    const int* __restrict__ cnt,
    int* __restrict__ row_start,   // [N+1]
    int* __restrict__ cursor,      // [N]
    int nNodes)
{
    __shared__ int s[1024];
    const int t = threadIdx.x;
    const int CH = (nNodes + 1023) / 1024;
    const int lo = t * CH;
    const int hi = min(nNodes, lo + CH);

    int local = 0;
    for (int i = lo; i < hi; ++i) local += cnt[i];
    s[t] = local;
    __syncthreads();
    // Hillis-Steele inclusive scan over 1024 partials
    for (int off = 1; off < 1024; off <<= 1) {
        int v = (t >= off) ? s[t - off] : 0;
        __syncthreads();
        s[t] += v;
        __syncthreads();
    }
    int run = s[t] - local;  // exclusive base
    for (int i = lo; i < hi; ++i) {
        row_start[i] = run;
        cursor[i] = run;
        run += cnt[i];
    }
    if (t == 1023) row_start[nNodes] = run;
}

__global__ __launch_bounds__(256) void fill_kernel(
    const int* __restrict__ ei, int* __restrict__ cursor,
    int* __restrict__ col, int E)
{
    int e = blockIdx.x * blockDim.x + threadIdx.x;
    if (e < E) {
        int src = ei[e];
        int dst = ei[E + e];
        int pos = atomicAdd(&cursor[dst], 1);
        col[pos] = src;
    }
}

// ---------------------------------------------------------------------------
// Gather-mean: half-wave (32 lanes, one float4 each) per dst node; accumulate
// neighbor rows in registers, write mean once. Block = 256 threads = 8 nodes.
// ---------------------------------------------------------------------------
__global__ __launch_bounds__(256) void gather_mean_kernel(
    const float* __restrict__ feat,
    const int* __restrict__ row_start,
    const int* __restrict__ col,
    float* __restrict__ aggm,       // [N,128] mean-aggregated output
    int nNodes)
{
    int node = blockIdx.x * 8 + (threadIdx.x >> 5);
    if (node >= nNodes) return;
    int c = threadIdx.x & 31;

    int rs = row_start[node];
    int re = row_start[node + 1];

    float4 a0 = {0.f, 0.f, 0.f, 0.f};
    float4 a1 = {0.f, 0.f, 0.f, 0.f};
    int j = rs;
    for (; j + 1 < re; j += 2) {
        int s0 = col[j], s1 = col[j + 1];
        float4 v0 = reinterpret_cast<const float4*>(feat)[(size_t)s0 * 32 + c];
        float4 v1 = reinterpret_cast<const float4*>(feat)[(size_t)s1 * 32 + c];
        a0.x += v0.x; a0.y += v0.y; a0.z += v0.z; a0.w += v0.w;
        a1.x += v1.x; a1.y += v1.y; a1.z += v1.z; a1.w += v1.w;
    }
    if (j < re) {
        int s0 = col[j];
        float4 v0 = reinterpret_cast<const float4*>(feat)[(size_t)s0 * 32 + c];
        a0.x += v0.x; a0.y += v0.y; a0.z += v0.z; a0.w += v0.w;
    }
    float inv = 1.0f / fmaxf((float)(re - rs), 1.0f);
    float4 r = {(a0.x + a1.x) * inv, (a0.y + a1.y) * inv,
                (a0.z + a1.z) * inv, (a0.w + a1.w) * inv};
    reinterpret_cast<float4*>(aggm)[(size_t)node * 32 + c] = r;
}

// ---------------------------------------------------------------------------
// Dense: out[n,:] = epilogue( aggm[n] @ Wl^T + b + feat[n] @ Wr^T )
// ---------------------------------------------------------------------------
template <int M, int EPI>  // EPI: 0 = relu, 1 = log_softmax
__global__ __launch_bounds__(256) void dense_kernel(
    const float* __restrict__ aggm,
    const float* __restrict__ feat,
    const float* __restrict__ Wl,   // [M,128]
    const float* __restrict__ b,    // [M]
    const float* __restrict__ Wr,   // [M,128]
    float* __restrict__ out)        // [N, M]
{
    constexpr int PO = M / 16;              // outputs per thread
    __shared__ float A[16][260];            // [node][k]; k<128 aggm, k>=128 feat; +4 pad

    const int t = threadIdx.x;
    const int nl = t >> 4;                  // node within block, 0..15
    const int oc = t & 15;                  // output group, 0..15
    const int gbase = blockIdx.x * 16;

    // Stage A tile: 16 nodes x 256 floats = 1024 float4, 4 per thread.
    for (int i = 0; i < 4; ++i) {
        int idx = i * 256 + t;              // 0..1023
        int row = idx >> 6;                 // 0..15
        int c4  = idx & 63;                 // float4 index within 256 floats
        int g = gbase + row;
        float4 v;
        if (c4 < 32) {
            v = reinterpret_cast<const float4*>(aggm)[(size_t)g * 32 + c4];
        } else {
            v = reinterpret_cast<const float4*>(feat)[(size_t)g * 32 + (c4 - 32)];
        }
        reinterpret_cast<float4*>(&A[row][0])[c4] = v;
    }
    __syncthreads();

    float acc[PO];
#pragma unroll
    for (int j = 0; j < PO; ++j) acc[j] = b[oc * PO + j];

    // Phase 1: aggm @ Wl^T
#pragma unroll 4
    for (int k4 = 0; k4 < 32; ++k4) {
        float4 a = reinterpret_cast<const float4*>(&A[nl][0])[k4];
#pragma unroll
        for (int j = 0; j < PO; ++j) {
            float4 w = reinterpret_cast<const float4*>(Wl)[(oc * PO + j) * 32 + k4];
            acc[j] += a.x * w.x + a.y * w.y + a.z * w.z + a.w * w.w;
        }
    }
    // Phase 2: feat @ Wr^T
#pragma unroll 4
    for (int k4 = 0; k4 < 32; ++k4) {
        float4 a = reinterpret_cast<const float4*>(&A[nl][0])[32 + k4];
#pragma unroll
        for (int j = 0; j < PO; ++j) {
            float4 w = reinterpret_cast<const float4*>(Wr)[(oc * PO + j) * 32 + k4];
            acc[j] += a.x * w.x + a.y * w.y + a.z * w.z + a.w * w.w;
        }
    }

    const int g = gbase + nl;
    float* op = out + (size_t)g * M + oc * PO;

    if (EPI == 0) {
#pragma unroll
        for (int j = 0; j < PO; ++j) acc[j] = fmaxf(acc[j], 0.0f);
#pragma unroll
        for (int j4 = 0; j4 < PO / 4; ++j4) {
            float4 v = {acc[j4 * 4 + 0], acc[j4 * 4 + 1], acc[j4 * 4 + 2], acc[j4 * 4 + 3]};
            reinterpret_cast<float4*>(op)[j4] = v;
        }
    } else {
        float m = acc[0];
#pragma unroll
        for (int j = 1; j < PO; ++j) m = fmaxf(m, acc[j]);
#pragma unroll
        for (int s = 1; s < 16; s <<= 1) m = fmaxf(m, __shfl_xor(m, s, 16));
        float sum = 0.0f;
#pragma unroll
        for (int j = 0; j < PO; ++j) sum += expf(acc[j] - m);
#pragma unroll
        for (int s = 1; s < 16; s <<= 1) sum += __shfl_xor(sum, s, 16);
        float lse = m + logf(sum);
#pragma unroll
        for (int j4 = 0; j4 < PO / 4; ++j4) {
            float4 v = {acc[j4 * 4 + 0] - lse, acc[j4 * 4 + 1] - lse,
                        acc[j4 * 4 + 2] - lse, acc[j4 * 4 + 3] - lse};
            reinterpret_cast<float4*>(op)[j4] = v;
        }
    }
}

extern "C" void kernel_launch(void* const* d_in, const int* in_sizes, int n_in,
                              void* d_out, int out_size, void* d_ws, size_t ws_size,
                              hipStream_t stream)
{
    const float* x   = (const float*)d_in[0];
    const int*   ei  = (const int*)d_in[1];   // [2, E] int32
    const float* W1l = (const float*)d_in[2];
    const float* b1  = (const float*)d_in[3];
    const float* W1r = (const float*)d_in[4];
    const float* W2l = (const float*)d_in[5];
    const float* b2  = (const float*)d_in[6];
    const float* W2r = (const float*)d_in[7];
    float* out = (float*)d_out;

    const int E = in_sizes[1] / 2;

    // Workspace layout:
    //   int cnt[N] | int row_start[N+1] | int cursor[N] | int col[E] |
    //   (16B aligned) float aggm[N*128] | float h[N*128]
    int* cnt       = (int*)d_ws;
    int* row_start = cnt + N_NODES;
    int* cursor    = row_start + N_NODES + 1;
    int* col       = cursor + N_NODES;
    size_t off = (size_t)(3 * N_NODES + 1) + (size_t)E;
    off = (off + 31) & ~(size_t)31;          // 16B-align the float4 regions
    float* aggm = (float*)d_ws + off;
    float* h    = aggm + (size_t)N_NODES * 128;

    // Zero counts only (gather fully overwrites aggm/h).
    hipMemsetAsync(cnt, 0, (size_t)N_NODES * sizeof(int), stream);

    const int eb = (E + 255) / 256;
    const int nb = (N_NODES + 7) / 8;

    // CSR build (shared by both layers)
    count_kernel<<<eb, 256, 0, stream>>>(ei, cnt, E);
    scan_kernel<<<1, 1024, 0, stream>>>(cnt, row_start, cursor, N_NODES);
    fill_kernel<<<eb, 256, 0, stream>>>(ei, cursor, col, E);

    // Layer 1
    gather_mean_kernel<<<nb, 256, 0, stream>>>(x, row_start, col, aggm, N_NODES);
    dense_kernel<128, 0><<<N_NODES / 16, 256, 0, stream>>>(aggm, x, W1l, b1, W1r, h);

    // Layer 2
    gather_mean_kernel<<<nb, 256, 0, stream>>>(h, row_start, col, aggm, N_NODES);
    dense_kernel<64, 1><<<N_NODES / 16, 256, 0, stream>>>(aggm, h, W2l, b2, W2r, out);
}

// Round 3
// 278.179 us; speedup vs baseline: 11.8134x; 4.9329x over previous
//
#include <hip/hip_runtime.h>

#define N_NODES 50000
#define TILES (N_NODES / 16)   // 3125

typedef __bf16 v8bf __attribute__((ext_vector_type(8)));
typedef float v4f __attribute__((ext_vector_type(4)));

union ABfrag { uint4 u; v8bf v; };

__device__ __forceinline__ float bf2f(unsigned short u) {
    union { unsigned int i; float f; } c; c.i = ((unsigned int)u) << 16; return c.f;
}
__device__ __forceinline__ unsigned short f2bf(float f) {
    union { float f; unsigned int i; } c; c.f = f;
    unsigned int r = c.i + 0x7FFFu + ((c.i >> 16) & 1u);
    return (unsigned short)(r >> 16);
}

// ---------------------------------------------------------------------------
// CSR build: count -> scan -> fill (dst-sorted adjacency, gather-side mean).
// ---------------------------------------------------------------------------
__global__ __launch_bounds__(256) void count_kernel(
    const int* __restrict__ ei, int* __restrict__ cnt, int E)
{
    int e = blockIdx.x * blockDim.x + threadIdx.x;
    if (e < E) atomicAdd(&cnt[ei[E + e]], 1);
}

__global__ __launch_bounds__(1024) void scan_kernel(
    const int* __restrict__ cnt, int* __restrict__ row_start,
    int* __restrict__ cursor, int nNodes)
{
    __shared__ int s[1024];
    const int t = threadIdx.x;
    const int CH = (nNodes + 1023) / 1024;
    const int lo = t * CH;
    const int hi = min(nNodes, lo + CH);

    int local = 0;
    for (int i = lo; i < hi; ++i) local += cnt[i];
    s[t] = local;
    __syncthreads();
    for (int off = 1; off < 1024; off <<= 1) {
        int v = (t >= off) ? s[t - off] : 0;
        __syncthreads();
        s[t] += v;
        __syncthreads();
    }
    int run = s[t] - local;
    for (int i = lo; i < hi; ++i) {
        row_start[i] = run;
        cursor[i] = run;
        run += cnt[i];
    }
    if (t == 1023) row_start[nNodes] = run;
}

__global__ __launch_bounds__(256) void fill_kernel(
    const int* __restrict__ ei, int* __restrict__ cursor,
    int* __restrict__ col, int E)
{
    int e = blockIdx.x * blockDim.x + threadIdx.x;
    if (e < E) {
        int src = ei[e];
        int dst = ei[E + e];
        int pos = atomicAdd(&cursor[dst], 1);
        col[pos] = src;
    }
}

// ---------------------------------------------------------------------------
// fp32 -> bf16 bulk convert (8 elems/thread)
// ---------------------------------------------------------------------------
__global__ __launch_bounds__(256) void f32_to_bf16_kernel(
    const float* __restrict__ in, unsigned short* __restrict__ out, int n8)
{
    int i = blockIdx.x * blockDim.x + threadIdx.x;
    if (i >= n8) return;
    const float4* p = reinterpret_cast<const float4*>(in) + (size_t)i * 2;
    float4 a = p[0], b = p[1];
    uint4 o;
    o.x = (unsigned int)f2bf(a.x) | ((unsigned int)f2bf(a.y) << 16);
    o.y = (unsigned int)f2bf(a.z) | ((unsigned int)f2bf(a.w) << 16);
    o.z = (unsigned int)f2bf(b.x) | ((unsigned int)f2bf(b.y) << 16);
    o.w = (unsigned int)f2bf(b.z) | ((unsigned int)f2bf(b.w) << 16);
    reinterpret_cast<uint4*>(out)[i] = o;
}

// ---------------------------------------------------------------------------
// Pack Wcat^T (=[Wl;Wr] stacked along K) into MFMA B-fragment order:
// Wp[((ks*NFG + nf)*64 + lane)*8 + i] = Wcat[k][n]
//   k = ks*32 + 4*(lane>>4) + (i&3) + 16*(i>>2),  n = nf*16 + (lane&15)
// ---------------------------------------------------------------------------
__global__ __launch_bounds__(256) void pack_w_kernel(
    const float* __restrict__ Wl, const float* __restrict__ Wr,
    unsigned short* __restrict__ Wp, int NFG)
{
    int p = blockIdx.x * 256 + threadIdx.x;
    int total = NFG * 8 * 64 * 8;
    if (p >= total) return;
    int i = p & 7;
    int lane = (p >> 3) & 63;
    int q = p >> 9;              // = ks*NFG + nf
    int nf = q % NFG;
    int ks = q / NFG;
    int k = ks * 32 + 4 * (lane >> 4) + (i & 3) + 16 * (i >> 2);
    int n = nf * 16 + (lane & 15);
    float w = (k < 128) ? Wl[n * 128 + k] : Wr[n * 128 + (k - 128)];
    Wp[p] = f2bf(w);
}

// ---------------------------------------------------------------------------
// Gather-mean over bf16 features: 32 lanes/node, uint2 (4 bf16) per lane,
// fp32 accumulate, bf16 mean out.
// ---------------------------------------------------------------------------
__global__ __launch_bounds__(256) void gather_mean_bf16_kernel(
    const unsigned short* __restrict__ feat,  // [N,128] bf16
    const int* __restrict__ row_start,
    const int* __restrict__ col,
    unsigned short* __restrict__ aggm,        // [N,128] bf16
    int nNodes)
{
    int node = blockIdx.x * 8 + (threadIdx.x >> 5);
    if (node >= nNodes) return;
    int c = threadIdx.x & 31;
    int rs = row_start[node], re = row_start[node + 1];
    const uint2* f2 = reinterpret_cast<const uint2*>(feat);

    float a0 = 0.f, a1 = 0.f, a2 = 0.f, a3 = 0.f;
    float b0 = 0.f, b1 = 0.f, b2 = 0.f, b3 = 0.f;
    int j = rs;
    for (; j + 1 < re; j += 2) {
        uint2 u = f2[(size_t)col[j] * 32 + c];
        uint2 v = f2[(size_t)col[j + 1] * 32 + c];
        a0 += bf2f((unsigned short)u.x); a1 += bf2f((unsigned short)(u.x >> 16));
        a2 += bf2f((unsigned short)u.y); a3 += bf2f((unsigned short)(u.y >> 16));
        b0 += bf2f((unsigned short)v.x); b1 += bf2f((unsigned short)(v.x >> 16));
        b2 += bf2f((unsigned short)v.y); b3 += bf2f((unsigned short)(v.y >> 16));
    }
    if (j < re) {
        uint2 u = f2[(size_t)col[j] * 32 + c];
        a0 += bf2f((unsigned short)u.x); a1 += bf2f((unsigned short)(u.x >> 16));
        a2 += bf2f((unsigned short)u.y); a3 += bf2f((unsigned short)(u.y >> 16));
    }
    float inv = 1.0f / fmaxf((float)(re - rs), 1.0f);
    uint2 o;
    o.x = (unsigned int)f2bf((a0 + b0) * inv) | ((unsigned int)f2bf((a1 + b1) * inv) << 16);
    o.y = (unsigned int)f2bf((a2 + b2) * inv) | ((unsigned int)f2bf((a3 + b3) * inv) << 16);
    reinterpret_cast<uint2*>(aggm)[(size_t)node * 32 + c] = o;
}

// ---------------------------------------------------------------------------
// Dense layer 1 (MFMA): h = relu([aggm|x] @ Wcat + b), bf16 out.
// Block = 4 waves; wave w owns output cols [32w, 32w+32); 16-node tiles,
// grid-stride. W fragments live in VGPRs for the whole kernel.
// ---------------------------------------------------------------------------
__global__ __launch_bounds__(256) void dense1_mfma_kernel(
    const unsigned short* __restrict__ aggm,
    const unsigned short* __restrict__ xbf,
    const unsigned short* __restrict__ Wp,    // packed, NFG=8
    const float* __restrict__ bias,           // [128]
    unsigned short* __restrict__ h)           // [N,128] bf16
{
    __shared__ unsigned short A[2 * 16 * 136];  // [half][row][136], pad vs bank conflicts
    const int t = threadIdx.x;
    const int w = t >> 6;
    const int lane = t & 63;
    const int m = lane & 15;
    const int g = lane >> 4;

    ABfrag wf[2][8];
    const uint4* wp4 = reinterpret_cast<const uint4*>(Wp);
#pragma unroll
    for (int ks = 0; ks < 8; ++ks)
#pragma unroll
        for (int nf = 0; nf < 2; ++nf)
            wf[nf][ks].u = wp4[(size_t)(ks * 8 + (w * 2 + nf)) * 64 + lane];

    float bv0 = bias[w * 32 + m];
    float bv1 = bias[w * 32 + 16 + m];

    for (int tile = blockIdx.x; tile < TILES; tile += gridDim.x) {
        int nb0 = tile * 16;
        {
            int row = t >> 4, c = t & 15;
            uint4 v0 = reinterpret_cast<const uint4*>(aggm)[(size_t)(nb0 + row) * 16 + c];
            uint4 v1 = reinterpret_cast<const uint4*>(xbf )[(size_t)(nb0 + row) * 16 + c];
            *reinterpret_cast<uint4*>(&A[row * 136 + c * 8]) = v0;
            *reinterpret_cast<uint4*>(&A[2176 + row * 136 + c * 8]) = v1;
        }
        __syncthreads();

        v4f acc0 = {bv0, bv0, bv0, bv0};
        v4f acc1 = {bv1, bv1, bv1, bv1};
#pragma unroll
        for (int ks = 0; ks < 8; ++ks) {
            int half = ks >> 2, ksl = ks & 3;
            const unsigned short* base = &A[half * 2176 + m * 136 + ksl * 32 + 4 * g];
            uint2 lo = *reinterpret_cast<const uint2*>(base);
            uint2 hi = *reinterpret_cast<const uint2*>(base + 16);
            ABfrag af; af.u = make_uint4(lo.x, lo.y, hi.x, hi.y);
            acc0 = __builtin_amdgcn_mfma_f32_16x16x32_bf16(af.v, wf[0][ks].v, acc0, 0, 0, 0);
            acc1 = __builtin_amdgcn_mfma_f32_16x16x32_bf16(af.v, wf[1][ks].v, acc1, 0, 0, 0);
        }

#pragma unroll
        for (int r = 0; r < 4; ++r) {
            int node = nb0 + 4 * g + r;
            h[(size_t)node * 128 + w * 32 + m]      = f2bf(fmaxf(acc0[r], 0.f));
            h[(size_t)node * 128 + w * 32 + 16 + m] = f2bf(fmaxf(acc1[r], 0.f));
        }
        __syncthreads();
    }
}

// ---------------------------------------------------------------------------
// Dense layer 2 (MFMA): out = log_softmax([aggm2|h] @ Wcat2 + b2), fp32 out.
// Wave w owns output cols [16w, 16w+16); cross-wave softmax via LDS.
// ---------------------------------------------------------------------------
__global__ __launch_bounds__(256) void dense2_mfma_kernel(
    const unsigned short* __restrict__ aggm,
    const unsigned short* __restrict__ hbf,
    const unsigned short* __restrict__ Wp,    // packed, NFG=4
    const float* __restrict__ bias,           // [64]
    float* __restrict__ out)                  // [N,64]
{
    __shared__ unsigned short A[2 * 16 * 136];
    __shared__ float C[16 * 68];
    const int t = threadIdx.x;
    const int w = t >> 6;
    const int lane = t & 63;
    const int m = lane & 15;
    const int g = lane >> 4;

    ABfrag wf[8];
    const uint4* wp4 = reinterpret_cast<const uint4*>(Wp);
#pragma unroll
    for (int ks = 0; ks < 8; ++ks)
        wf[ks].u = wp4[(size_t)(ks * 4 + w) * 64 + lane];
    float bv = bias[w * 16 + m];

    for (int tile = blockIdx.x; tile < TILES; tile += gridDim.x) {
        int nb0 = tile * 16;
        {
            int row = t >> 4, c = t & 15;
            uint4 v0 = reinterpret_cast<const uint4*>(aggm)[(size_t)(nb0 + row) * 16 + c];
            uint4 v1 = reinterpret_cast<const uint4*>(hbf )[(size_t)(nb0 + row) * 16 + c];
            *reinterpret_cast<uint4*>(&A[row * 136 + c * 8]) = v0;
            *reinterpret_cast<uint4*>(&A[2176 + row * 136 + c * 8]) = v1;
        }
        __syncthreads();

        v4f acc = {bv, bv, bv, bv};
#pragma unroll
        for (int ks = 0; ks < 8; ++ks) {
            int half = ks >> 2, ksl = ks & 3;
            const unsigned short* base = &A[half * 2176 + m * 136 + ksl * 32 + 4 * g];
            uint2 lo = *reinterpret_cast<const uint2*>(base);
            uint2 hi = *reinterpret_cast<const uint2*>(base + 16);
            ABfrag af; af.u = make_uint4(lo.x, lo.y, hi.x, hi.y);
            acc = __builtin_amdgcn_mfma_f32_16x16x32_bf16(af.v, wf[ks].v, acc, 0, 0, 0);
        }

#pragma unroll
        for (int r = 0; r < 4; ++r)
            C[(4 * g + r) * 68 + w * 16 + m] = acc[r];
        __syncthreads();

        {
            int node = t >> 4, c = t & 15;
            float v0 = C[node * 68 + c],      v1 = C[node * 68 + 16 + c];
            float v2 = C[node * 68 + 32 + c], v3 = C[node * 68 + 48 + c];
            float mx = fmaxf(fmaxf(v0, v1), fmaxf(v2, v3));
#pragma unroll
            for (int s = 1; s < 16; s <<= 1) mx = fmaxf(mx, __shfl_xor(mx, s, 16));
            float sum = expf(v0 - mx) + expf(v1 - mx) + expf(v2 - mx) + expf(v3 - mx);
#pragma unroll
            for (int s = 1; s < 16; s <<= 1) sum += __shfl_xor(sum, s, 16);
            float lse = mx + logf(sum);
            float* op = out + (size_t)(nb0 + node) * 64;
            op[c]      = v0 - lse; op[c + 16] = v1 - lse;
            op[c + 32] = v2 - lse; op[c + 48] = v3 - lse;
        }
        __syncthreads();
    }
}

extern "C" void kernel_launch(void* const* d_in, const int* in_sizes, int n_in,
                              void* d_out, int out_size, void* d_ws, size_t ws_size,
                              hipStream_t stream)
{
    const float* x   = (const float*)d_in[0];
    const int*   ei  = (const int*)d_in[1];
    const float* W1l = (const float*)d_in[2];
    const float* b1  = (const float*)d_in[3];
    const float* W1r = (const float*)d_in[4];
    const float* W2l = (const float*)d_in[5];
    const float* b2  = (const float*)d_in[6];
    const float* W2r = (const float*)d_in[7];
    float* out = (float*)d_out;

    const int E = in_sizes[1] / 2;

    // ws: cnt[N] | row_start[N+1] | cursor[N] | col[E] | (16B align)
    //     xbf[N*128] | aggm[N*128] | hbf[N*128] | Wp1[32768] | Wp2[16384]  (bf16)
    int* cnt       = (int*)d_ws;
    int* row_start = cnt + N_NODES;
    int* cursor    = row_start + N_NODES + 1;
    int* col       = cursor + N_NODES;
    size_t off_i = (size_t)(3 * N_NODES + 1) + (size_t)E;
    off_i = (off_i + 3) & ~(size_t)3;              // align to 16B (4 ints)
    unsigned short* xbf  = (unsigned short*)((int*)d_ws + off_i);
    unsigned short* aggm = xbf  + (size_t)N_NODES * 128;
    unsigned short* hbf  = aggm + (size_t)N_NODES * 128;
    unsigned short* Wp1  = hbf  + (size_t)N_NODES * 128;
    unsigned short* Wp2  = Wp1 + 32768;

    hipMemsetAsync(cnt, 0, (size_t)N_NODES * sizeof(int), stream);

    const int eb = (E + 255) / 256;
    const int nb = N_NODES / 8;

    count_kernel<<<eb, 256, 0, stream>>>(ei, cnt, E);
    scan_kernel<<<1, 1024, 0, stream>>>(cnt, row_start, cursor, N_NODES);
    fill_kernel<<<eb, 256, 0, stream>>>(ei, cursor, col, E);

    f32_to_bf16_kernel<<<(N_NODES * 128 / 8 + 255) / 256, 256, 0, stream>>>(x, xbf, N_NODES * 128 / 8);
    pack_w_kernel<<<128, 256, 0, stream>>>(W1l, W1r, Wp1, 8);
    pack_w_kernel<<<64, 256, 0, stream>>>(W2l, W2r, Wp2, 4);

    // Layer 1
    gather_mean_bf16_kernel<<<nb, 256, 0, stream>>>(xbf, row_start, col, aggm, N_NODES);
    dense1_mfma_kernel<<<1024, 256, 0, stream>>>(aggm, xbf, Wp1, b1, hbf);

    // Layer 2
    gather_mean_bf16_kernel<<<nb, 256, 0, stream>>>(hbf, row_start, col, aggm, N_NODES);
    dense2_mfma_kernel<<<1024, 256, 0, stream>>>(aggm, hbf, Wp2, b2, out);
}

// Round 4
// 181.144 us; speedup vs baseline: 18.1417x; 1.5357x over previous
//
#include <hip/hip_runtime.h>

#define N_NODES 50000
#define TILES (N_NODES / 16)   // 3125
#define SCAN_BLOCKS ((N_NODES + 255) / 256)   // 196

typedef __bf16 v8bf __attribute__((ext_vector_type(8)));
typedef float v4f __attribute__((ext_vector_type(4)));

union ABfrag { uint4 u; v8bf v; };

__device__ __forceinline__ float bf2f(unsigned short u) {
    union { unsigned int i; float f; } c; c.i = ((unsigned int)u) << 16; return c.f;
}
__device__ __forceinline__ unsigned short f2bf(float f) {
    union { float f; unsigned int i; } c; c.f = f;
    unsigned int r = c.i + 0x7FFFu + ((c.i >> 16) & 1u);
    return (unsigned short)(r >> 16);
}

// ---------------------------------------------------------------------------
// CSR build: count -> 3-phase scan -> fill.
// ---------------------------------------------------------------------------
__global__ __launch_bounds__(256) void count_kernel(
    const int* __restrict__ ei, int* __restrict__ cnt, int E)
{
    int e = blockIdx.x * blockDim.x + threadIdx.x;
    if (e < E) atomicAdd(&cnt[ei[E + e]], 1);
}

// Phase A: per-block partial sums of cnt (256 elems/block, coalesced).
__global__ __launch_bounds__(256) void scanA_kernel(
    const int* __restrict__ cnt, int* __restrict__ bsum, int n)
{
    int i = blockIdx.x * 256 + threadIdx.x;
    int v = (i < n) ? cnt[i] : 0;
#pragma unroll
    for (int s = 32; s; s >>= 1) v += __shfl_down(v, s, 64);
    __shared__ int ws[4];
    int lane = threadIdx.x & 63, wid = threadIdx.x >> 6;
    if (lane == 0) ws[wid] = v;
    __syncthreads();
    if (threadIdx.x == 0) bsum[blockIdx.x] = ws[0] + ws[1] + ws[2] + ws[3];
}

// Phase B: one block scans the block partials -> exclusive bases; total -> row_start[N].
__global__ __launch_bounds__(256) void scanB_kernel(
    int* __restrict__ bsum, int* __restrict__ row_start, int nB, int nNodes)
{
    __shared__ int s[256];
    int t = threadIdx.x;
    int v = (t < nB) ? bsum[t] : 0;
    s[t] = v;
    __syncthreads();
#pragma unroll
    for (int off = 1; off < 256; off <<= 1) {
        int u = (t >= off) ? s[t - off] : 0;
        __syncthreads();
        s[t] += u;
        __syncthreads();
    }
    if (t < nB) bsum[t] = s[t] - v;          // exclusive base
    if (t == 255) row_start[nNodes] = s[255]; // total (= E)
}

// Phase C: block-local exclusive scan + base -> row_start / cursor.
__global__ __launch_bounds__(256) void scanC_kernel(
    const int* __restrict__ cnt, const int* __restrict__ bsum,
    int* __restrict__ row_start, int* __restrict__ cursor, int n)
{
    __shared__ int s[256];
    int t = threadIdx.x;
    int i = blockIdx.x * 256 + t;
    int v = (i < n) ? cnt[i] : 0;
    s[t] = v;
    __syncthreads();
#pragma unroll
    for (int off = 1; off < 256; off <<= 1) {
        int u = (t >= off) ? s[t - off] : 0;
        __syncthreads();
        s[t] += u;
        __syncthreads();
    }
    if (i < n) {
        int ex = bsum[blockIdx.x] + s[t] - v;
        row_start[i] = ex;
        cursor[i] = ex;
    }
}

__global__ __launch_bounds__(256) void fill_kernel(
    const int* __restrict__ ei, int* __restrict__ cursor,
    int* __restrict__ col, int E)
{
    int e = blockIdx.x * blockDim.x + threadIdx.x;
    if (e < E) {
        int src = ei[e];
        int dst = ei[E + e];
        int pos = atomicAdd(&cursor[dst], 1);
        col[pos] = src;
    }
}

// ---------------------------------------------------------------------------
// fp32 -> bf16 bulk convert (8 elems/thread)
// ---------------------------------------------------------------------------
__global__ __launch_bounds__(256) void f32_to_bf16_kernel(
    const float* __restrict__ in, unsigned short* __restrict__ out, int n8)
{
    int i = blockIdx.x * blockDim.x + threadIdx.x;
    if (i >= n8) return;
    const float4* p = reinterpret_cast<const float4*>(in) + (size_t)i * 2;
    float4 a = p[0], b = p[1];
    uint4 o;
    o.x = (unsigned int)f2bf(a.x) | ((unsigned int)f2bf(a.y) << 16);
    o.y = (unsigned int)f2bf(a.z) | ((unsigned int)f2bf(a.w) << 16);
    o.z = (unsigned int)f2bf(b.x) | ((unsigned int)f2bf(b.y) << 16);
    o.w = (unsigned int)f2bf(b.z) | ((unsigned int)f2bf(b.w) << 16);
    reinterpret_cast<uint4*>(out)[i] = o;
}

// ---------------------------------------------------------------------------
// Pack Wcat^T into MFMA B-fragment order (see round-3 comment).
// ---------------------------------------------------------------------------
__global__ __launch_bounds__(256) void pack_w_kernel(
    const float* __restrict__ Wl, const float* __restrict__ Wr,
    unsigned short* __restrict__ Wp, int NFG)
{
    int p = blockIdx.x * 256 + threadIdx.x;
    int total = NFG * 8 * 64 * 8;
    if (p >= total) return;
    int i = p & 7;
    int lane = (p >> 3) & 63;
    int q = p >> 9;
    int nf = q % NFG;
    int ks = q / NFG;
    int k = ks * 32 + 4 * (lane >> 4) + (i & 3) + 16 * (i >> 2);
    int n = nf * 16 + (lane & 15);
    float w = (k < 128) ? Wl[n * 128 + k] : Wr[n * 128 + (k - 128)];
    Wp[p] = f2bf(w);
}

// ---------------------------------------------------------------------------
// Gather-mean over bf16 features: 32 lanes/node, fp32 accumulate, bf16 out.
// ---------------------------------------------------------------------------
__global__ __launch_bounds__(256) void gather_mean_bf16_kernel(
    const unsigned short* __restrict__ feat,
    const int* __restrict__ row_start,
    const int* __restrict__ col,
    unsigned short* __restrict__ aggm,
    int nNodes)
{
    int node = blockIdx.x * 8 + (threadIdx.x >> 5);
    if (node >= nNodes) return;
    int c = threadIdx.x & 31;
    int rs = row_start[node], re = row_start[node + 1];
    const uint2* f2 = reinterpret_cast<const uint2*>(feat);

    float a0 = 0.f, a1 = 0.f, a2 = 0.f, a3 = 0.f;
    float b0 = 0.f, b1 = 0.f, b2 = 0.f, b3 = 0.f;
    int j = rs;
    for (; j + 1 < re; j += 2) {
        uint2 u = f2[(size_t)col[j] * 32 + c];
        uint2 v = f2[(size_t)col[j + 1] * 32 + c];
        a0 += bf2f((unsigned short)u.x); a1 += bf2f((unsigned short)(u.x >> 16));
        a2 += bf2f((unsigned short)u.y); a3 += bf2f((unsigned short)(u.y >> 16));
        b0 += bf2f((unsigned short)v.x); b1 += bf2f((unsigned short)(v.x >> 16));
        b2 += bf2f((unsigned short)v.y); b3 += bf2f((unsigned short)(v.y >> 16));
    }
    if (j < re) {
        uint2 u = f2[(size_t)col[j] * 32 + c];
        a0 += bf2f((unsigned short)u.x); a1 += bf2f((unsigned short)(u.x >> 16));
        a2 += bf2f((unsigned short)u.y); a3 += bf2f((unsigned short)(u.y >> 16));
    }
    float inv = 1.0f / fmaxf((float)(re - rs), 1.0f);
    uint2 o;
    o.x = (unsigned int)f2bf((a0 + b0) * inv) | ((unsigned int)f2bf((a1 + b1) * inv) << 16);
    o.y = (unsigned int)f2bf((a2 + b2) * inv) | ((unsigned int)f2bf((a3 + b3) * inv) << 16);
    reinterpret_cast<uint2*>(aggm)[(size_t)node * 32 + c] = o;
}

// ---------------------------------------------------------------------------
// Dense layer 1 (MFMA): h = relu([aggm|x] @ Wcat + b), bf16 out.
// ---------------------------------------------------------------------------
__global__ __launch_bounds__(256) void dense1_mfma_kernel(
    const unsigned short* __restrict__ aggm,
    const unsigned short* __restrict__ xbf,
    const unsigned short* __restrict__ Wp,
    const float* __restrict__ bias,
    unsigned short* __restrict__ h)
{
    __shared__ unsigned short A[2 * 16 * 136];
    const int t = threadIdx.x;
    const int w = t >> 6;
    const int lane = t & 63;
    const int m = lane & 15;
    const int g = lane >> 4;

    ABfrag wf[2][8];
    const uint4* wp4 = reinterpret_cast<const uint4*>(Wp);
#pragma unroll
    for (int ks = 0; ks < 8; ++ks)
#pragma unroll
        for (int nf = 0; nf < 2; ++nf)
            wf[nf][ks].u = wp4[(size_t)(ks * 8 + (w * 2 + nf)) * 64 + lane];

    float bv0 = bias[w * 32 + m];
    float bv1 = bias[w * 32 + 16 + m];

    for (int tile = blockIdx.x; tile < TILES; tile += gridDim.x) {
        int nb0 = tile * 16;
        {
            int row = t >> 4, c = t & 15;
            uint4 v0 = reinterpret_cast<const uint4*>(aggm)[(size_t)(nb0 + row) * 16 + c];
            uint4 v1 = reinterpret_cast<const uint4*>(xbf )[(size_t)(nb0 + row) * 16 + c];
            *reinterpret_cast<uint4*>(&A[row * 136 + c * 8]) = v0;
            *reinterpret_cast<uint4*>(&A[2176 + row * 136 + c * 8]) = v1;
        }
        __syncthreads();

        v4f acc0 = {bv0, bv0, bv0, bv0};
        v4f acc1 = {bv1, bv1, bv1, bv1};
#pragma unroll
        for (int ks = 0; ks < 8; ++ks) {
            int half = ks >> 2, ksl = ks & 3;
            const unsigned short* base = &A[half * 2176 + m * 136 + ksl * 32 + 4 * g];
            uint2 lo = *reinterpret_cast<const uint2*>(base);
            uint2 hi = *reinterpret_cast<const uint2*>(base + 16);
            ABfrag af; af.u = make_uint4(lo.x, lo.y, hi.x, hi.y);
            acc0 = __builtin_amdgcn_mfma_f32_16x16x32_bf16(af.v, wf[0][ks].v, acc0, 0, 0, 0);
            acc1 = __builtin_amdgcn_mfma_f32_16x16x32_bf16(af.v, wf[1][ks].v, acc1, 0, 0, 0);
        }

#pragma unroll
        for (int r = 0; r < 4; ++r) {
            int node = nb0 + 4 * g + r;
            h[(size_t)node * 128 + w * 32 + m]      = f2bf(fmaxf(acc0[r], 0.f));
            h[(size_t)node * 128 + w * 32 + 16 + m] = f2bf(fmaxf(acc1[r], 0.f));
        }
        __syncthreads();
    }
}

// ---------------------------------------------------------------------------
// Dense layer 2 (MFMA): out = log_softmax([aggm2|h] @ Wcat2 + b2), fp32 out.
// ---------------------------------------------------------------------------
__global__ __launch_bounds__(256) void dense2_mfma_kernel(
    const unsigned short* __restrict__ aggm,
    const unsigned short* __restrict__ hbf,
    const unsigned short* __restrict__ Wp,
    const float* __restrict__ bias,
    float* __restrict__ out)
{
    __shared__ unsigned short A[2 * 16 * 136];
    __shared__ float C[16 * 68];
    const int t = threadIdx.x;
    const int w = t >> 6;
    const int lane = t & 63;
    const int m = lane & 15;
    const int g = lane >> 4;

    ABfrag wf[8];
    const uint4* wp4 = reinterpret_cast<const uint4*>(Wp);
#pragma unroll
    for (int ks = 0; ks < 8; ++ks)
        wf[ks].u = wp4[(size_t)(ks * 4 + w) * 64 + lane];
    float bv = bias[w * 16 + m];

    for (int tile = blockIdx.x; tile < TILES; tile += gridDim.x) {
        int nb0 = tile * 16;
        {
            int row = t >> 4, c = t & 15;
            uint4 v0 = reinterpret_cast<const uint4*>(aggm)[(size_t)(nb0 + row) * 16 + c];
            uint4 v1 = reinterpret_cast<const uint4*>(hbf )[(size_t)(nb0 + row) * 16 + c];
            *reinterpret_cast<uint4*>(&A[row * 136 + c * 8]) = v0;
            *reinterpret_cast<uint4*>(&A[2176 + row * 136 + c * 8]) = v1;
        }
        __syncthreads();

        v4f acc = {bv, bv, bv, bv};
#pragma unroll
        for (int ks = 0; ks < 8; ++ks) {
            int half = ks >> 2, ksl = ks & 3;
            const unsigned short* base = &A[half * 2176 + m * 136 + ksl * 32 + 4 * g];
            uint2 lo = *reinterpret_cast<const uint2*>(base);
            uint2 hi = *reinterpret_cast<const uint2*>(base + 16);
            ABfrag af; af.u = make_uint4(lo.x, lo.y, hi.x, hi.y);
            acc = __builtin_amdgcn_mfma_f32_16x16x32_bf16(af.v, wf[ks].v, acc, 0, 0, 0);
        }

#pragma unroll
        for (int r = 0; r < 4; ++r)
            C[(4 * g + r) * 68 + w * 16 + m] = acc[r];
        __syncthreads();

        {
            int node = t >> 4, c = t & 15;
            float v0 = C[node * 68 + c],      v1 = C[node * 68 + 16 + c];
            float v2 = C[node * 68 + 32 + c], v3 = C[node * 68 + 48 + c];
            float mx = fmaxf(fmaxf(v0, v1), fmaxf(v2, v3));
#pragma unroll
            for (int s = 1; s < 16; s <<= 1) mx = fmaxf(mx, __shfl_xor(mx, s, 16));
            float sum = expf(v0 - mx) + expf(v1 - mx) + expf(v2 - mx) + expf(v3 - mx);
#pragma unroll
            for (int s = 1; s < 16; s <<= 1) sum += __shfl_xor(sum, s, 16);
            float lse = mx + logf(sum);
            float* op = out + (size_t)(nb0 + node) * 64;
            op[c]      = v0 - lse; op[c + 16] = v1 - lse;
            op[c + 32] = v2 - lse; op[c + 48] = v3 - lse;
        }
        __syncthreads();
    }
}

extern "C" void kernel_launch(void* const* d_in, const int* in_sizes, int n_in,
                              void* d_out, int out_size, void* d_ws, size_t ws_size,
                              hipStream_t stream)
{
    const float* x   = (const float*)d_in[0];
    const int*   ei  = (const int*)d_in[1];
    const float* W1l = (const float*)d_in[2];
    const float* b1  = (const float*)d_in[3];
    const float* W1r = (const float*)d_in[4];
    const float* W2l = (const float*)d_in[5];
    const float* b2  = (const float*)d_in[6];
    const float* W2r = (const float*)d_in[7];
    float* out = (float*)d_out;

    const int E = in_sizes[1] / 2;

    // ws: cnt[N] | row_start[N+1] | cursor[N] | bsum[256] | col[E] | (16B align)
    //     xbf[N*128] | aggm[N*128] | hbf[N*128] | Wp1[32768] | Wp2[16384]  (bf16)
    int* cnt       = (int*)d_ws;
    int* row_start = cnt + N_NODES;
    int* cursor    = row_start + N_NODES + 1;
    int* bsum      = cursor + N_NODES;
    int* col       = bsum + 256;
    size_t off_i = (size_t)(3 * N_NODES + 1 + 256) + (size_t)E;
    off_i = (off_i + 3) & ~(size_t)3;
    unsigned short* xbf  = (unsigned short*)((int*)d_ws + off_i);
    unsigned short* aggm = xbf  + (size_t)N_NODES * 128;
    unsigned short* hbf  = aggm + (size_t)N_NODES * 128;
    unsigned short* Wp1  = hbf  + (size_t)N_NODES * 128;
    unsigned short* Wp2  = Wp1 + 32768;

    hipMemsetAsync(cnt, 0, (size_t)N_NODES * sizeof(int), stream);

    const int eb = (E + 255) / 256;
    const int nb = N_NODES / 8;

    count_kernel<<<eb, 256, 0, stream>>>(ei, cnt, E);
    scanA_kernel<<<SCAN_BLOCKS, 256, 0, stream>>>(cnt, bsum, N_NODES);
    scanB_kernel<<<1, 256, 0, stream>>>(bsum, row_start, SCAN_BLOCKS, N_NODES);
    scanC_kernel<<<SCAN_BLOCKS, 256, 0, stream>>>(cnt, bsum, row_start, cursor, N_NODES);
    fill_kernel<<<eb, 256, 0, stream>>>(ei, cursor, col, E);

    f32_to_bf16_kernel<<<(N_NODES * 128 / 8 + 255) / 256, 256, 0, stream>>>(x, xbf, N_NODES * 128 / 8);
    pack_w_kernel<<<128, 256, 0, stream>>>(W1l, W1r, Wp1, 8);
    pack_w_kernel<<<64, 256, 0, stream>>>(W2l, W2r, Wp2, 4);

    // Layer 1
    gather_mean_bf16_kernel<<<nb, 256, 0, stream>>>(xbf, row_start, col, aggm, N_NODES);
    dense1_mfma_kernel<<<1024, 256, 0, stream>>>(aggm, xbf, Wp1, b1, hbf);

    // Layer 2
    gather_mean_bf16_kernel<<<nb, 256, 0, stream>>>(hbf, row_start, col, aggm, N_NODES);
    dense2_mfma_kernel<<<1024, 256, 0, stream>>>(aggm, hbf, Wp2, b2, out);
}